// Round 1
// baseline (1834.570 us; speedup 1.0000x reference)
//
#include <hip/hip_runtime.h>

#define N_TOT 211072   // B*V = 32*6596
#define V_MESH 6596
#define E_TOT 633216   // 3*N
#define HDIM 128
#define CAP 32

__constant__ float c_LIM[14] = {0.04f,0.06f,0.04f,0.04f,0.02f,0.02f,0.04f,0.04f,
                                0.03f,0.03f,0.02f,0.02f,0.01f,0.01f};

// ---------------- adjacency build ----------------
__global__ __launch_bounds__(256) void fill_adj_kernel(const int* __restrict__ edges,
                                                       int* __restrict__ cnt,
                                                       int* __restrict__ adj) {
    int e = blockIdx.x * 256 + threadIdx.x;
    if (e >= E_TOT) return;
    int2 ed = ((const int2*)edges)[e];
    int p0 = atomicAdd(&cnt[ed.x], 1);
    if (p0 < CAP) adj[(size_t)ed.x * CAP + p0] = ed.y;
    int p1 = atomicAdd(&cnt[ed.y], 1);
    if (p1 < CAP) adj[(size_t)ed.y * CAP + p1] = ed.x;
}

// ---------------- layer 0 matmul (feats = normals, d=3) ----------------
__global__ __launch_bounds__(256) void mm3_kernel(const float* __restrict__ normals,
                                                  const float* __restrict__ w0,
                                                  const float* __restrict__ b0,
                                                  const float* __restrict__ w1,
                                                  const float* __restrict__ b1,
                                                  float* __restrict__ x0out,
                                                  float* __restrict__ x1out) {
    __shared__ float nL[32][3];
    int t = threadIdx.x;
    int row0 = blockIdx.x * 32;
    if (t < 96) {
        int r = t / 3, k = t - r * 3;
        nL[r][k] = normals[(size_t)(row0 + r) * 3 + k];
    }
    __syncthreads();
    int m = t >> 7;          // 0 -> w0, 1 -> w1
    int c = t & 127;
    const float* w = m ? w1 : w0;
    const float* b = m ? b1 : b0;
    float w00 = w[0 * 128 + c], w01 = w[1 * 128 + c], w02 = w[2 * 128 + c];
    float bb = b[c];
    float* outp = m ? x1out : x0out;
    #pragma unroll 8
    for (int r = 0; r < 32; ++r) {
        float v = bb + nL[r][0] * w00 + nL[r][1] * w01 + nL[r][2] * w02;
        outp[(size_t)(row0 + r) * 128 + c] = v;
    }
}

// ---------------- layer 1/2 matmul (feats = [h(128), normals(3)]) ----------------
// In-place safe: block reads only its own 32 rows of A into LDS, writes them at the end.
__global__ __launch_bounds__(256) void mm131_kernel(const float* __restrict__ A, // h, post-relu
                                                    const float* __restrict__ normals,
                                                    const float* __restrict__ w0,
                                                    const float* __restrict__ b0,
                                                    const float* __restrict__ w1,
                                                    const float* __restrict__ b1,
                                                    float* __restrict__ x0out,  // may alias A
                                                    float* __restrict__ x1out) {
    __shared__ float fL[32][132];          // feats tile (pad 132 keeps 16B align)
    __shared__ float wL[2][32][128];       // K-chunk of both weight mats
    __shared__ float wnL[2][3][128];       // normals-part weights (k=128..130)

    int t = threadIdx.x;
    int row0 = blockIdx.x * 32;

    // load h part of feats: 32x128 floats = 1024 float4
    const float4* A4 = (const float4*)(A + (size_t)row0 * 128);
    #pragma unroll
    for (int i = 0; i < 4; ++i) {
        int idx = t + i * 256;
        int r = idx >> 5, c4 = idx & 31;
        *(float4*)&fL[r][c4 * 4] = A4[r * 32 + c4];
    }
    // normals part
    if (t < 96) {
        int r = t / 3, k = t - r * 3;
        fL[r][128 + k] = normals[(size_t)(row0 + r) * 3 + k];
    }
    // normals-part weights: 2*3*128 = 768 floats
    for (int i = t; i < 768; i += 256) {
        int mm = i >> 8;            // /384? no: 768/2=384 -> use explicit math below
        int rem = i - mm * 384;
        // careful: mm = i/384
        mm = i / 384; rem = i - mm * 384;
        int k = rem >> 7, c = rem & 127;
        wnL[mm][k][c] = (mm ? w1 : w0)[(size_t)(128 + k) * 128 + c];
    }

    int m  = t >> 7;         // matrix
    int rh = (t >> 6) & 1;   // row half
    int c0 = t & 63;         // columns c0 and c0+64
    const float* bb = m ? b1 : b0;
    float acc[16][2];
    {
        float bias0 = bb[c0], bias1 = bb[c0 + 64];
        #pragma unroll
        for (int r = 0; r < 16; ++r) { acc[r][0] = bias0; acc[r][1] = bias1; }
    }

    for (int kk = 0; kk < 128; kk += 32) {
        __syncthreads();   // protect wL against previous chunk's readers
        // load wL[2][32][128] = 2048 float4
        #pragma unroll
        for (int i = 0; i < 8; ++i) {
            int idx = t + i * 256;
            int mm = idx >> 10;
            int rem = idx & 1023;
            int k = rem >> 5, c4 = rem & 31;
            *(float4*)&wL[mm][k][c4 * 4] =
                ((const float4*)((mm ? w1 : w0) + (size_t)(kk + k) * 128))[c4];
        }
        __syncthreads();
        #pragma unroll
        for (int k4 = 0; k4 < 32; k4 += 4) {
            float wa[4], wb[4];
            #pragma unroll
            for (int j = 0; j < 4; ++j) {
                wa[j] = wL[m][k4 + j][c0];
                wb[j] = wL[m][k4 + j][c0 + 64];
            }
            #pragma unroll
            for (int r = 0; r < 16; ++r) {
                float4 f = *(const float4*)&fL[rh * 16 + r][kk + k4];
                acc[r][0] += f.x * wa[0] + f.y * wa[1] + f.z * wa[2] + f.w * wa[3];
                acc[r][1] += f.x * wb[0] + f.y * wb[1] + f.z * wb[2] + f.w * wb[3];
            }
        }
    }
    // normals columns (k = 128..130)
    #pragma unroll
    for (int j = 0; j < 3; ++j) {
        float wn0 = wnL[m][j][c0];
        float wn1 = wnL[m][j][c0 + 64];
        #pragma unroll
        for (int r = 0; r < 16; ++r) {
            float f = fL[rh * 16 + r][128 + j];
            acc[r][0] += f * wn0;
            acc[r][1] += f * wn1;
        }
    }
    float* outp = m ? x1out : x0out;
    #pragma unroll
    for (int r = 0; r < 16; ++r) {
        size_t row = row0 + rh * 16 + r;
        outp[row * 128 + c0]      = acc[r][0];
        outp[row * 128 + c0 + 64] = acc[r][1];
    }
}

// ---------------- neighbor gather + relu (in-place on A) ----------------
__global__ __launch_bounds__(256) void agg_kernel(const float* __restrict__ A,   // x0
                                                  const float* __restrict__ X,   // x1
                                                  const int* __restrict__ cnt,
                                                  const int* __restrict__ adj,
                                                  float* __restrict__ out) {     // h (may alias A)
    int i = blockIdx.x * 4 + (threadIdx.x >> 6);
    int lane = threadIdx.x & 63;
    float2 acc = ((const float2*)A)[(size_t)i * 64 + lane];
    int deg = cnt[i]; if (deg > CAP) deg = CAP;
    int j = (lane < deg) ? adj[(size_t)i * CAP + lane] : 0;
    for (int k = 0; k < deg; ++k) {
        int jj = __shfl(j, k);
        float2 xv = ((const float2*)X)[(size_t)jj * 64 + lane];
        acc.x += xv.x; acc.y += xv.y;
    }
    acc.x = fmaxf(acc.x, 0.f);
    acc.y = fmaxf(acc.y, 0.f);
    ((float2*)out)[(size_t)i * 64 + lane] = acc;
}

// ---------------- final: deform + clamp + vertex update ----------------
__global__ __launch_bounds__(256) void final_kernel(const float* __restrict__ h,      // OUTH
                                                    const float* __restrict__ normals,
                                                    const float* __restrict__ verts,
                                                    const float* __restrict__ anchor_v,
                                                    const int* __restrict__ part_id,
                                                    const float* __restrict__ w_off,
                                                    const float* __restrict__ b_off,
                                                    float* __restrict__ out_verts) {
    __shared__ float wo[131 * 3];
    for (int i = threadIdx.x; i < 131 * 3; i += 256) wo[i] = w_off[i];
    __syncthreads();
    int i = blockIdx.x * 4 + (threadIdx.x >> 6);
    int lane = threadIdx.x & 63;
    float2 h2 = ((const float2*)h)[(size_t)i * 64 + lane];
    int k0 = 2 * lane, k1 = 2 * lane + 1;
    float s0 = h2.x * wo[k0 * 3 + 0] + h2.y * wo[k1 * 3 + 0];
    float s1 = h2.x * wo[k0 * 3 + 1] + h2.y * wo[k1 * 3 + 1];
    float s2 = h2.x * wo[k0 * 3 + 2] + h2.y * wo[k1 * 3 + 2];
    #pragma unroll
    for (int d = 32; d; d >>= 1) {
        s0 += __shfl_xor(s0, d);
        s1 += __shfl_xor(s1, d);
        s2 += __shfl_xor(s2, d);
    }
    if (lane < 3) {
        int v = i % V_MESH;
        float n0 = normals[(size_t)i * 3 + 0];
        float n1 = normals[(size_t)i * 3 + 1];
        float n2 = normals[(size_t)i * 3 + 2];
        float s = (lane == 0) ? s0 : (lane == 1) ? s1 : s2;
        s += n0 * wo[128 * 3 + lane] + n1 * wo[129 * 3 + lane] + n2 * wo[130 * 3 + lane];
        s += b_off[lane];
        float d = tanhf(s);
        float lim = c_LIM[part_id[v]];
        d = fminf(fmaxf(d, -lim), lim);
        out_verts[(size_t)i * 3 + lane] =
            verts[(size_t)i * 3 + lane] + d * anchor_v[(size_t)v * 3 + lane];
    }
}

extern "C" void kernel_launch(void* const* d_in, const int* in_sizes, int n_in,
                              void* d_out, int out_size, void* d_ws, size_t ws_size,
                              hipStream_t stream) {
    const float* verts    = (const float*)d_in[0];
    const float* normals  = (const float*)d_in[1];
    const float* anchor_v = (const float*)d_in[2];
    const int*   edges    = (const int*)d_in[3];
    const int*   part_id  = (const int*)d_in[4];
    const float* w0_0 = (const float*)d_in[5];
    const float* b0_0 = (const float*)d_in[6];
    const float* w1_0 = (const float*)d_in[7];
    const float* b1_0 = (const float*)d_in[8];
    const float* w0_1 = (const float*)d_in[9];
    const float* b0_1 = (const float*)d_in[10];
    const float* w1_1 = (const float*)d_in[11];
    const float* b1_1 = (const float*)d_in[12];
    const float* w0_2 = (const float*)d_in[13];
    const float* b0_2 = (const float*)d_in[14];
    const float* w1_2 = (const float*)d_in[15];
    const float* b1_2 = (const float*)d_in[16];
    const float* w_off = (const float*)d_in[17];
    const float* b_off = (const float*)d_in[18];

    float* out_verts = (float*)d_out;
    float* A = (float*)d_out + (size_t)3 * N_TOT;   // h region of d_out doubles as accumulator

    // workspace: X (N*128 f32) | cnt (N int) | adj (N*CAP int)
    float* X  = (float*)d_ws;
    int* cnt  = (int*)((char*)d_ws + (size_t)N_TOT * 128 * 4);
    int* adj  = cnt + N_TOT;

    hipMemsetAsync(cnt, 0, (size_t)N_TOT * 4, stream);
    fill_adj_kernel<<<(E_TOT + 255) / 256, 256, 0, stream>>>(edges, cnt, adj);

    // layer 0
    mm3_kernel<<<N_TOT / 32, 256, 0, stream>>>(normals, w0_0, b0_0, w1_0, b1_0, A, X);
    agg_kernel<<<N_TOT / 4, 256, 0, stream>>>(A, X, cnt, adj, A);
    // layer 1
    mm131_kernel<<<N_TOT / 32, 256, 0, stream>>>(A, normals, w0_1, b0_1, w1_1, b1_1, A, X);
    agg_kernel<<<N_TOT / 4, 256, 0, stream>>>(A, X, cnt, adj, A);
    // layer 2
    mm131_kernel<<<N_TOT / 32, 256, 0, stream>>>(A, normals, w0_2, b0_2, w1_2, b1_2, A, X);
    agg_kernel<<<N_TOT / 4, 256, 0, stream>>>(A, X, cnt, adj, A);
    // epilogue
    final_kernel<<<N_TOT / 4, 256, 0, stream>>>(A, normals, verts, anchor_v, part_id,
                                                w_off, b_off, out_verts);
}

// Round 2
// 719.808 us; speedup vs baseline: 2.5487x; 2.5487x over previous
//
#include <hip/hip_runtime.h>

#define N_TOT 211072   // B*V = 32*6596
#define V_MESH 6596
#define E_TOT 633216   // 3*N
#define CAP 32
#define KP 184         // padded feats width (bf16 elems); 368B rows -> 2-way LDS banks (free)
#define KSTEPS 5       // 5*32 = 160 >= 131

typedef __attribute__((ext_vector_type(8))) short bf16x8;
typedef __attribute__((ext_vector_type(4))) float f32x4;

__constant__ float c_LIM[14] = {0.04f,0.06f,0.04f,0.04f,0.02f,0.02f,0.04f,0.04f,
                                0.03f,0.03f,0.02f,0.02f,0.01f,0.01f};

__device__ __forceinline__ unsigned f2bf(float f) {   // RNE f32->bf16 (bits in low 16)
    unsigned x = __float_as_uint(f);
    return (x + 0x7fffu + ((x >> 16) & 1u)) >> 16;
}
__device__ __forceinline__ float bf2f(unsigned lo16) {
    return __uint_as_float(lo16 << 16);
}

// ---------------- adjacency build ----------------
__global__ __launch_bounds__(256) void fill_adj_kernel(const int* __restrict__ edges,
                                                       int* __restrict__ cnt,
                                                       int* __restrict__ adj) {
    int e = blockIdx.x * 256 + threadIdx.x;
    if (e >= E_TOT) return;
    int2 ed = ((const int2*)edges)[e];
    int p0 = atomicAdd(&cnt[ed.x], 1);
    if (p0 < CAP) adj[(size_t)ed.x * CAP + p0] = ed.y;
    int p1 = atomicAdd(&cnt[ed.y], 1);
    if (p1 < CAP) adj[(size_t)ed.y * CAP + p1] = ed.x;
}

// ---------------- featsB static part: cols 128..130 = bf16(normals), 131..183 = 0 ----------------
__global__ __launch_bounds__(256) void prep_feats_kernel(const float* __restrict__ normals,
                                                         short* __restrict__ featsB) {
    int i = blockIdx.x * 256 + threadIdx.x;
    if (i >= N_TOT) return;
    unsigned short v[56] = {};                 // zero-init, static indexing only
    v[0] = (unsigned short)f2bf(normals[(size_t)i * 3 + 0]);
    v[1] = (unsigned short)f2bf(normals[(size_t)i * 3 + 1]);
    v[2] = (unsigned short)f2bf(normals[(size_t)i * 3 + 2]);
    uint4* dst = (uint4*)(featsB + (size_t)i * KP + 128);   // byte off i*368+256, 16B aligned
    #pragma unroll
    for (int q = 0; q < 7; ++q) dst[q] = ((const uint4*)v)[q];
}

// ---------------- weight conversion: Wt[256][184] bf16 (transposed, zero-padded), bb[256] ----------------
__global__ __launch_bounds__(256) void conv_w_kernel(const float* __restrict__ w0,
                                                     const float* __restrict__ b0,
                                                     const float* __restrict__ w1,
                                                     const float* __restrict__ b1,
                                                     short* __restrict__ Wt,
                                                     float* __restrict__ bb) {
    int c = blockIdx.x;          // 0..255 output col (0-127 -> w0, 128-255 -> w1)
    int k = threadIdx.x;         // 0..255
    const float* w = (c < 128) ? w0 : w1;
    int cc = c & 127;
    if (k < KP) {
        unsigned val = (k < 131) ? f2bf(w[(size_t)k * 128 + cc]) : 0u;
        Wt[(size_t)c * KP + k] = (short)val;
    }
    if (k == 0) bb[c] = (c < 128) ? b0[cc] : b1[cc];
}

// ---------------- layer 0 matmul (feats = normals, d=3) ----------------
__global__ __launch_bounds__(256) void mm3_kernel(const float* __restrict__ normals,
                                                  const float* __restrict__ w0,
                                                  const float* __restrict__ b0,
                                                  const float* __restrict__ w1,
                                                  const float* __restrict__ b1,
                                                  float* __restrict__ x0out,    // f32 [N][128]
                                                  short* __restrict__ x1out) {  // bf16 [N][128]
    __shared__ float nL[32][3];
    int t = threadIdx.x;
    int row0 = blockIdx.x * 32;
    if (t < 96) {
        int r = t / 3, k = t - r * 3;
        nL[r][k] = normals[(size_t)(row0 + r) * 3 + k];
    }
    __syncthreads();
    int m = t >> 7;          // 0 -> w0, 1 -> w1
    int c = t & 127;
    const float* w = m ? w1 : w0;
    const float* b = m ? b1 : b0;
    float w00 = w[0 * 128 + c], w01 = w[1 * 128 + c], w02 = w[2 * 128 + c];
    float bbv = b[c];
    #pragma unroll 8
    for (int r = 0; r < 32; ++r) {
        float v = bbv + nL[r][0] * w00 + nL[r][1] * w01 + nL[r][2] * w02;
        if (m) x1out[(size_t)(row0 + r) * 128 + c] = (short)f2bf(v);
        else   x0out[(size_t)(row0 + r) * 128 + c] = v;
    }
}

// ---------------- MFMA matmul: [32 rows] x [K=160(pad)] @ Wt -> x0 (f32), x1 (bf16) ----------------
__global__ __launch_bounds__(256) void mm_mfma_kernel(const short* __restrict__ featsB, // [N][184] bf16
                                                      const short* __restrict__ Wt,     // [256][184] bf16
                                                      const float* __restrict__ bb,     // [256]
                                                      float* __restrict__ x0out,        // [N][128] f32
                                                      short* __restrict__ x1out) {      // [N][128] bf16
    __shared__ short tileA[768 * 8];    // 12288 B: 32 rows x 184 + overshoot pad
    int tid  = threadIdx.x;
    int w    = tid >> 6;
    int lane = tid & 63;
    int ln15 = lane & 15;
    int kg   = lane >> 4;
    int row0 = blockIdx.x * 32;
    int cb0  = w * 64;

    // ---- stage A tile (32x184 bf16 = 736 chunks; issue 768 to keep waves uniform) ----
    const short* src = featsB + (size_t)row0 * KP;
    #pragma unroll
    for (int r = 0; r < 3; ++r) {
        int cbase = r * 256 + w * 64;   // wave-uniform chunk base (16B units)
        __builtin_amdgcn_global_load_lds(
            (const __attribute__((address_space(1))) unsigned*)(src + (size_t)(cbase + lane) * 8),
            (__attribute__((address_space(3))) unsigned*)(tileA + cbase * 8),
            16, 0, 0);
    }

    // ---- preload B fragments (L2-resident weights) while staging is in flight ----
    bf16x8 bfrag[KSTEPS][4];
    #pragma unroll
    for (int kk = 0; kk < KSTEPS; ++kk)
        #pragma unroll
        for (int cf = 0; cf < 4; ++cf) {
            int col = cb0 + cf * 16 + ln15;
            bfrag[kk][cf] = *(const bf16x8*)(Wt + (size_t)col * KP + kk * 32 + kg * 8);
        }

    f32x4 acc[2][4];
    #pragma unroll
    for (int cf = 0; cf < 4; ++cf) {
        float bv = bb[cb0 + cf * 16 + ln15];
        acc[0][cf] = (f32x4){bv, bv, bv, bv};
        acc[1][cf] = (f32x4){bv, bv, bv, bv};
    }

    __syncthreads();   // drains vmcnt -> tile + bfrags ready

    #pragma unroll
    for (int kk = 0; kk < KSTEPS; ++kk) {
        bf16x8 a0 = *(const bf16x8*)(tileA + (0  + ln15) * KP + kk * 32 + kg * 8);
        bf16x8 a1 = *(const bf16x8*)(tileA + (16 + ln15) * KP + kk * 32 + kg * 8);
        #pragma unroll
        for (int cf = 0; cf < 4; ++cf) {
            acc[0][cf] = __builtin_amdgcn_mfma_f32_16x16x32_bf16(a0, bfrag[kk][cf], acc[0][cf], 0, 0, 0);
            acc[1][cf] = __builtin_amdgcn_mfma_f32_16x16x32_bf16(a1, bfrag[kk][cf], acc[1][cf], 0, 0, 0);
        }
    }

    // ---- store: waves 0,1 -> x0 f32; waves 2,3 -> x1 bf16 (wave-uniform branch) ----
    if (cb0 < 128) {
        #pragma unroll
        for (int rf = 0; rf < 2; ++rf)
            #pragma unroll
            for (int cf = 0; cf < 4; ++cf) {
                int col = cb0 + cf * 16 + ln15;
                int rbase = row0 + rf * 16 + kg * 4;
                #pragma unroll
                for (int j = 0; j < 4; ++j)
                    x0out[(size_t)(rbase + j) * 128 + col] = acc[rf][cf][j];
            }
    } else {
        #pragma unroll
        for (int rf = 0; rf < 2; ++rf)
            #pragma unroll
            for (int cf = 0; cf < 4; ++cf) {
                int col = cb0 + cf * 16 + ln15 - 128;
                int rbase = row0 + rf * 16 + kg * 4;
                #pragma unroll
                for (int j = 0; j < 4; ++j)
                    x1out[(size_t)(rbase + j) * 128 + col] = (short)f2bf(acc[rf][cf][j]);
            }
    }
}

// ---------------- neighbor gather + relu ----------------
template<int LAST>
__global__ __launch_bounds__(256) void agg_kernel(const float* __restrict__ x0,      // [N][128] f32
                                                  const unsigned* __restrict__ x1,   // [N][64] 2xbf16
                                                  const int* __restrict__ cnt,
                                                  const int* __restrict__ adj,
                                                  short* __restrict__ featsB,        // [N][184]
                                                  float* __restrict__ hout) {        // aliases x0 rows
    int i = blockIdx.x * 4 + (threadIdx.x >> 6);
    int lane = threadIdx.x & 63;
    float2 acc = ((const float2*)x0)[(size_t)i * 64 + lane];
    int deg = cnt[i]; if (deg > CAP) deg = CAP;
    int j = (lane < deg) ? adj[(size_t)i * CAP + lane] : 0;
    for (int k = 0; k < deg; ++k) {
        int jj = __shfl(j, k);
        unsigned u = x1[(size_t)jj * 64 + lane];
        acc.x += bf2f(u & 0xffffu);
        acc.y += bf2f(u >> 16);
    }
    acc.x = fmaxf(acc.x, 0.f);
    acc.y = fmaxf(acc.y, 0.f);
    if (LAST) {
        ((float2*)hout)[(size_t)i * 64 + lane] = acc;   // own row: safe in-place over x0
    } else {
        unsigned lo = f2bf(acc.x), hi = f2bf(acc.y);
        ((unsigned*)featsB)[(size_t)i * (KP / 2) + lane] = lo | (hi << 16);
    }
}

// ---------------- final: deform + clamp + vertex update ----------------
__global__ __launch_bounds__(256) void final_kernel(const float* __restrict__ h,
                                                    const float* __restrict__ normals,
                                                    const float* __restrict__ verts,
                                                    const float* __restrict__ anchor_v,
                                                    const int* __restrict__ part_id,
                                                    const float* __restrict__ w_off,
                                                    const float* __restrict__ b_off,
                                                    float* __restrict__ out_verts) {
    __shared__ float wo[131 * 3];
    for (int i = threadIdx.x; i < 131 * 3; i += 256) wo[i] = w_off[i];
    __syncthreads();
    int i = blockIdx.x * 4 + (threadIdx.x >> 6);
    int lane = threadIdx.x & 63;
    float2 h2 = ((const float2*)h)[(size_t)i * 64 + lane];
    int k0 = 2 * lane, k1 = 2 * lane + 1;
    float s0 = h2.x * wo[k0 * 3 + 0] + h2.y * wo[k1 * 3 + 0];
    float s1 = h2.x * wo[k0 * 3 + 1] + h2.y * wo[k1 * 3 + 1];
    float s2 = h2.x * wo[k0 * 3 + 2] + h2.y * wo[k1 * 3 + 2];
    #pragma unroll
    for (int d = 32; d; d >>= 1) {
        s0 += __shfl_xor(s0, d);
        s1 += __shfl_xor(s1, d);
        s2 += __shfl_xor(s2, d);
    }
    if (lane < 3) {
        int v = i % V_MESH;
        float n0 = normals[(size_t)i * 3 + 0];
        float n1 = normals[(size_t)i * 3 + 1];
        float n2 = normals[(size_t)i * 3 + 2];
        float s = (lane == 0) ? s0 : (lane == 1) ? s1 : s2;
        s += n0 * wo[128 * 3 + lane] + n1 * wo[129 * 3 + lane] + n2 * wo[130 * 3 + lane];
        s += b_off[lane];
        float d = tanhf(s);
        float lim = c_LIM[part_id[v]];
        d = fminf(fmaxf(d, -lim), lim);
        out_verts[(size_t)i * 3 + lane] =
            verts[(size_t)i * 3 + lane] + d * anchor_v[(size_t)v * 3 + lane];
    }
}

extern "C" void kernel_launch(void* const* d_in, const int* in_sizes, int n_in,
                              void* d_out, int out_size, void* d_ws, size_t ws_size,
                              hipStream_t stream) {
    const float* verts    = (const float*)d_in[0];
    const float* normals  = (const float*)d_in[1];
    const float* anchor_v = (const float*)d_in[2];
    const int*   edges    = (const int*)d_in[3];
    const int*   part_id  = (const int*)d_in[4];
    const float* w0_0 = (const float*)d_in[5];
    const float* b0_0 = (const float*)d_in[6];
    const float* w1_0 = (const float*)d_in[7];
    const float* b1_0 = (const float*)d_in[8];
    const float* w0_1 = (const float*)d_in[9];
    const float* b0_1 = (const float*)d_in[10];
    const float* w1_1 = (const float*)d_in[11];
    const float* b1_1 = (const float*)d_in[12];
    const float* w0_2 = (const float*)d_in[13];
    const float* b0_2 = (const float*)d_in[14];
    const float* w1_2 = (const float*)d_in[15];
    const float* b1_2 = (const float*)d_in[16];
    const float* w_off = (const float*)d_in[17];
    const float* b_off = (const float*)d_in[18];

    float* out_verts = (float*)d_out;
    float* X0 = (float*)d_out + (size_t)3 * N_TOT;   // h region doubles as x0 accumulator / final h

    char* p = (char*)d_ws;
    short* featsB = (short*)p;   p += (size_t)N_TOT * KP * 2;
    short* X1     = (short*)p;   p += (size_t)N_TOT * 128 * 2;
    int*   cnt    = (int*)p;     p += (size_t)N_TOT * 4;
    int*   adj    = (int*)p;     p += (size_t)N_TOT * CAP * 4;
    short* Wt1    = (short*)p;   p += 256 * KP * 2;
    float* bb1    = (float*)p;   p += 256 * 4;
    short* Wt2    = (short*)p;   p += 256 * KP * 2;
    float* bb2    = (float*)p;

    hipMemsetAsync(cnt, 0, (size_t)N_TOT * 4, stream);
    fill_adj_kernel<<<(E_TOT + 255) / 256, 256, 0, stream>>>(edges, cnt, adj);
    prep_feats_kernel<<<(N_TOT + 255) / 256, 256, 0, stream>>>(normals, featsB);
    conv_w_kernel<<<256, 256, 0, stream>>>(w0_1, b0_1, w1_1, b1_1, Wt1, bb1);
    conv_w_kernel<<<256, 256, 0, stream>>>(w0_2, b0_2, w1_2, b1_2, Wt2, bb2);

    // layer 0
    mm3_kernel<<<N_TOT / 32, 256, 0, stream>>>(normals, w0_0, b0_0, w1_0, b1_0, X0, X1);
    agg_kernel<0><<<N_TOT / 4, 256, 0, stream>>>(X0, (const unsigned*)X1, cnt, adj, featsB, X0);
    // layer 1
    mm_mfma_kernel<<<N_TOT / 32, 256, 0, stream>>>(featsB, Wt1, bb1, X0, X1);
    agg_kernel<0><<<N_TOT / 4, 256, 0, stream>>>(X0, (const unsigned*)X1, cnt, adj, featsB, X0);
    // layer 2
    mm_mfma_kernel<<<N_TOT / 32, 256, 0, stream>>>(featsB, Wt2, bb2, X0, X1);
    agg_kernel<1><<<N_TOT / 4, 256, 0, stream>>>(X0, (const unsigned*)X1, cnt, adj, featsB, X0);
    // epilogue
    final_kernel<<<N_TOT / 4, 256, 0, stream>>>(X0, normals, verts, anchor_v, part_id,
                                                w_off, b_off, out_verts);
}

// Round 3
// 586.422 us; speedup vs baseline: 3.1284x; 1.2275x over previous
//
#include <hip/hip_runtime.h>

#define N_TOT 211072   // B*V = 32*6596
#define V_MESH 6596
#define E_TOT 633216   // 3*N
#define CAP 32
#define KP 184         // padded feats width (bf16); 368B rows -> 2-way LDS banks (free)
#define KSTEPS 5       // 5*32 = 160 >= 131

typedef __attribute__((ext_vector_type(8))) short bf16x8;
typedef __attribute__((ext_vector_type(4))) float f32x4;

__constant__ float c_LIM[14] = {0.04f,0.06f,0.04f,0.04f,0.02f,0.02f,0.04f,0.04f,
                                0.03f,0.03f,0.02f,0.02f,0.01f,0.01f};

__device__ __forceinline__ unsigned f2bf(float f) {   // RNE f32->bf16 (bits in low 16)
    unsigned x = __float_as_uint(f);
    return (x + 0x7fffu + ((x >> 16) & 1u)) >> 16;
}
__device__ __forceinline__ float bf2f(unsigned lo16) {
    return __uint_as_float(lo16 << 16);
}
__device__ __forceinline__ float2 unpk(unsigned u) {
    float2 r; r.x = bf2f(u & 0xffffu); r.y = bf2f(u >> 16); return r;
}

// ---------------- adjacency build ----------------
__global__ __launch_bounds__(256) void fill_adj_kernel(const int* __restrict__ edges,
                                                       int* __restrict__ cnt,
                                                       int* __restrict__ adj) {
    int e = blockIdx.x * 256 + threadIdx.x;
    if (e >= E_TOT) return;
    int2 ed = ((const int2*)edges)[e];
    int p0 = atomicAdd(&cnt[ed.x], 1);
    if (p0 < CAP) adj[(size_t)ed.x * CAP + p0] = ed.y;
    int p1 = atomicAdd(&cnt[ed.y], 1);
    if (p1 < CAP) adj[(size_t)ed.y * CAP + p1] = ed.x;
}

// ---------------- weight conversion: Wt[256][184] bf16 (transposed, zero-padded), bb[256] ----------------
__global__ __launch_bounds__(256) void conv_w_kernel(const float* __restrict__ w0,
                                                     const float* __restrict__ b0,
                                                     const float* __restrict__ w1,
                                                     const float* __restrict__ b1,
                                                     short* __restrict__ Wt,
                                                     float* __restrict__ bb) {
    int c = blockIdx.x;          // 0..255 output col (0-127 -> w0, 128-255 -> w1)
    int k = threadIdx.x;         // 0..255
    const float* w = (c < 128) ? w0 : w1;
    int cc = c & 127;
    if (k < KP) {
        unsigned val = (k < 131) ? f2bf(w[(size_t)k * 128 + cc]) : 0u;
        Wt[(size_t)c * KP + k] = (short)val;
    }
    if (k == 0) bb[c] = (c < 128) ? b0[cc] : b1[cc];
}

// ---------------- layer 0 matmul (feats = normals, d=3); both outputs bf16 ----------------
__global__ __launch_bounds__(256) void mm3_kernel(const float* __restrict__ normals,
                                                  const float* __restrict__ w0,
                                                  const float* __restrict__ b0,
                                                  const float* __restrict__ w1,
                                                  const float* __restrict__ b1,
                                                  short* __restrict__ x0out,   // bf16 [N][128]
                                                  short* __restrict__ x1out) { // bf16 [N][128]
    __shared__ float nL[32][3];
    int t = threadIdx.x;
    int row0 = blockIdx.x * 32;
    if (t < 96) {
        int r = t / 3, k = t - r * 3;
        nL[r][k] = normals[(size_t)(row0 + r) * 3 + k];
    }
    __syncthreads();
    int m = t >> 7;          // 0 -> w0, 1 -> w1
    int c = t & 127;
    const float* w = m ? w1 : w0;
    const float* b = m ? b1 : b0;
    float w00 = w[0 * 128 + c], w01 = w[1 * 128 + c], w02 = w[2 * 128 + c];
    float bbv = b[c];
    short* outp = m ? x1out : x0out;
    #pragma unroll 8
    for (int r = 0; r < 32; ++r) {
        float v = bbv + nL[r][0] * w00 + nL[r][1] * w01 + nL[r][2] * w02;
        outp[(size_t)(row0 + r) * 128 + c] = (short)f2bf(v);
    }
}

// ---------------- fused: gather+relu -> LDS tile -> MFMA GEMM -> x0',x1' (bf16) ----------------
__global__ __launch_bounds__(256) void fused_kernel(const unsigned* __restrict__ x0in, // [N][64] bf16x2
                                                    const unsigned* __restrict__ x1in, // [N][64] bf16x2
                                                    const float* __restrict__ normals,
                                                    const int* __restrict__ cnt,
                                                    const int* __restrict__ adj,
                                                    const short* __restrict__ Wt,     // [256][184]
                                                    const float* __restrict__ bb,     // [256]
                                                    short* __restrict__ x0out,        // [N][128] bf16
                                                    short* __restrict__ x1out) {      // [N][128] bf16
    __shared__ short tileA[32 * KP];   // 11776 B
    int tid  = threadIdx.x;
    int w    = tid >> 6;
    int lane = tid & 63;
    int ln15 = lane & 15;
    int kg   = lane >> 4;
    int row0 = blockIdx.x * 32;
    int cb0  = w * 64;

    // ---- preload B fragments (weights, L2/L3-resident) ----
    bf16x8 bfrag[KSTEPS][4];
    #pragma unroll
    for (int kk = 0; kk < KSTEPS; ++kk)
        #pragma unroll
        for (int cf = 0; cf < 4; ++cf) {
            int col = cb0 + cf * 16 + ln15;
            bfrag[kk][cf] = *(const bf16x8*)(Wt + (size_t)col * KP + kk * 32 + kg * 8);
        }

    f32x4 acc[2][4];
    #pragma unroll
    for (int cf = 0; cf < 4; ++cf) {
        float bv = bb[cb0 + cf * 16 + ln15];
        acc[0][cf] = (f32x4){bv, bv, bv, bv};
        acc[1][cf] = (f32x4){bv, bv, bv, bv};
    }

    // ---- gather + relu for this wave's 8 nodes, write tile rows ----
    unsigned* tile32 = (unsigned*)tileA;   // 92 dwords per row
    #pragma unroll
    for (int s = 0; s < 8; ++s) {
        int i = row0 + w * 8 + s;
        int deg = cnt[i]; deg = (deg > CAP) ? CAP : deg;
        int jv = (lane < CAP) ? adj[(size_t)i * CAP + lane] : 0;
        float2 a = unpk(x0in[(size_t)i * 64 + lane]);
        int kend = deg & ~3;
        int k = 0;
        for (; k < kend; k += 4) {      // 4 gathers in flight
            int j0 = __shfl(jv, k), j1 = __shfl(jv, k + 1);
            int j2 = __shfl(jv, k + 2), j3 = __shfl(jv, k + 3);
            unsigned u0 = x1in[(size_t)j0 * 64 + lane];
            unsigned u1 = x1in[(size_t)j1 * 64 + lane];
            unsigned u2 = x1in[(size_t)j2 * 64 + lane];
            unsigned u3 = x1in[(size_t)j3 * 64 + lane];
            float2 f0 = unpk(u0), f1 = unpk(u1), f2 = unpk(u2), f3 = unpk(u3);
            a.x += (f0.x + f1.x) + (f2.x + f3.x);
            a.y += (f0.y + f1.y) + (f2.y + f3.y);
        }
        for (; k < deg; ++k) {
            int jj = __shfl(jv, k);
            float2 f = unpk(x1in[(size_t)jj * 64 + lane]);
            a.x += f.x; a.y += f.y;
        }
        a.x = fmaxf(a.x, 0.f);
        a.y = fmaxf(a.y, 0.f);
        int r = w * 8 + s;
        tile32[r * (KP / 2) + lane] = f2bf(a.x) | (f2bf(a.y) << 16);
        // cols 128..183: normals + zero pad (dwords 64..91)
        float nvf = (lane < 3) ? normals[(size_t)i * 3 + lane] : 0.f;
        unsigned nv = f2bf(nvf);
        unsigned lo = __shfl(nv, 2 * lane);
        unsigned hi = __shfl(nv, 2 * lane + 1);
        if (lane < 28) tile32[r * (KP / 2) + 64 + lane] = (lane < 2) ? (lo | (hi << 16)) : 0u;
    }

    __syncthreads();

    #pragma unroll
    for (int kk = 0; kk < KSTEPS; ++kk) {
        bf16x8 a0 = *(const bf16x8*)(tileA + (0  + ln15) * KP + kk * 32 + kg * 8);
        bf16x8 a1 = *(const bf16x8*)(tileA + (16 + ln15) * KP + kk * 32 + kg * 8);
        #pragma unroll
        for (int cf = 0; cf < 4; ++cf) {
            acc[0][cf] = __builtin_amdgcn_mfma_f32_16x16x32_bf16(a0, bfrag[kk][cf], acc[0][cf], 0, 0, 0);
            acc[1][cf] = __builtin_amdgcn_mfma_f32_16x16x32_bf16(a1, bfrag[kk][cf], acc[1][cf], 0, 0, 0);
        }
    }

    short* outp = (cb0 < 128) ? x0out : x1out;
    int colb = cb0 & 127;
    #pragma unroll
    for (int rf = 0; rf < 2; ++rf)
        #pragma unroll
        for (int cf = 0; cf < 4; ++cf) {
            int col = colb + cf * 16 + ln15;
            int rbase = row0 + rf * 16 + kg * 4;
            #pragma unroll
            for (int j = 0; j < 4; ++j)
                outp[(size_t)(rbase + j) * 128 + col] = (short)f2bf(acc[rf][cf][j]);
        }
}

// ---------------- final: gather+relu -> h (f32) + deform + clamp + vertex update ----------------
__global__ __launch_bounds__(256) void final_fused_kernel(const unsigned* __restrict__ x0in,
                                                          const unsigned* __restrict__ x1in,
                                                          const int* __restrict__ cnt,
                                                          const int* __restrict__ adj,
                                                          const float* __restrict__ normals,
                                                          const float* __restrict__ verts,
                                                          const float* __restrict__ anchor_v,
                                                          const int* __restrict__ part_id,
                                                          const float* __restrict__ w_off,
                                                          const float* __restrict__ b_off,
                                                          float* __restrict__ hout,
                                                          float* __restrict__ out_verts) {
    __shared__ float wo[131 * 3];
    for (int t = threadIdx.x; t < 131 * 3; t += 256) wo[t] = w_off[t];
    __syncthreads();
    int i = blockIdx.x * 4 + (threadIdx.x >> 6);
    int lane = threadIdx.x & 63;

    int deg = cnt[i]; deg = (deg > CAP) ? CAP : deg;
    int jv = (lane < CAP) ? adj[(size_t)i * CAP + lane] : 0;
    float2 a = unpk(x0in[(size_t)i * 64 + lane]);
    int kend = deg & ~3;
    int k = 0;
    for (; k < kend; k += 4) {
        int j0 = __shfl(jv, k), j1 = __shfl(jv, k + 1);
        int j2 = __shfl(jv, k + 2), j3 = __shfl(jv, k + 3);
        unsigned u0 = x1in[(size_t)j0 * 64 + lane];
        unsigned u1 = x1in[(size_t)j1 * 64 + lane];
        unsigned u2 = x1in[(size_t)j2 * 64 + lane];
        unsigned u3 = x1in[(size_t)j3 * 64 + lane];
        float2 f0 = unpk(u0), f1 = unpk(u1), f2 = unpk(u2), f3 = unpk(u3);
        a.x += (f0.x + f1.x) + (f2.x + f3.x);
        a.y += (f0.y + f1.y) + (f2.y + f3.y);
    }
    for (; k < deg; ++k) {
        int jj = __shfl(jv, k);
        float2 f = unpk(x1in[(size_t)jj * 64 + lane]);
        a.x += f.x; a.y += f.y;
    }
    a.x = fmaxf(a.x, 0.f);
    a.y = fmaxf(a.y, 0.f);
    ((float2*)hout)[(size_t)i * 64 + lane] = a;

    int k0 = 2 * lane, k1 = 2 * lane + 1;
    float s0 = a.x * wo[k0 * 3 + 0] + a.y * wo[k1 * 3 + 0];
    float s1 = a.x * wo[k0 * 3 + 1] + a.y * wo[k1 * 3 + 1];
    float s2 = a.x * wo[k0 * 3 + 2] + a.y * wo[k1 * 3 + 2];
    #pragma unroll
    for (int d = 32; d; d >>= 1) {
        s0 += __shfl_xor(s0, d);
        s1 += __shfl_xor(s1, d);
        s2 += __shfl_xor(s2, d);
    }
    if (lane < 3) {
        int v = i % V_MESH;
        float n0 = normals[(size_t)i * 3 + 0];
        float n1 = normals[(size_t)i * 3 + 1];
        float n2 = normals[(size_t)i * 3 + 2];
        float s = (lane == 0) ? s0 : (lane == 1) ? s1 : s2;
        s += n0 * wo[128 * 3 + lane] + n1 * wo[129 * 3 + lane] + n2 * wo[130 * 3 + lane];
        s += b_off[lane];
        float d = tanhf(s);
        float lim = c_LIM[part_id[v]];
        d = fminf(fmaxf(d, -lim), lim);
        out_verts[(size_t)i * 3 + lane] =
            verts[(size_t)i * 3 + lane] + d * anchor_v[(size_t)v * 3 + lane];
    }
}

extern "C" void kernel_launch(void* const* d_in, const int* in_sizes, int n_in,
                              void* d_out, int out_size, void* d_ws, size_t ws_size,
                              hipStream_t stream) {
    const float* verts    = (const float*)d_in[0];
    const float* normals  = (const float*)d_in[1];
    const float* anchor_v = (const float*)d_in[2];
    const int*   edges    = (const int*)d_in[3];
    const int*   part_id  = (const int*)d_in[4];
    const float* w0_0 = (const float*)d_in[5];
    const float* b0_0 = (const float*)d_in[6];
    const float* w1_0 = (const float*)d_in[7];
    const float* b1_0 = (const float*)d_in[8];
    const float* w0_1 = (const float*)d_in[9];
    const float* b0_1 = (const float*)d_in[10];
    const float* w1_1 = (const float*)d_in[11];
    const float* b1_1 = (const float*)d_in[12];
    const float* w0_2 = (const float*)d_in[13];
    const float* b0_2 = (const float*)d_in[14];
    const float* w1_2 = (const float*)d_in[15];
    const float* b1_2 = (const float*)d_in[16];
    const float* w_off = (const float*)d_in[17];
    const float* b_off = (const float*)d_in[18];

    float* out_verts = (float*)d_out;
    float* hout = (float*)d_out + (size_t)3 * N_TOT;      // final h (f32)

    // pair B aliases the (dead until the end) h region: 2 x 54 MB bf16
    unsigned* x0B = (unsigned*)hout;
    unsigned* x1B = x0B + (size_t)N_TOT * 64;

    char* p = (char*)d_ws;
    unsigned* x0A = (unsigned*)p;  p += (size_t)N_TOT * 64 * 4;
    unsigned* x1A = (unsigned*)p;  p += (size_t)N_TOT * 64 * 4;
    int*   cnt    = (int*)p;       p += (size_t)N_TOT * 4;
    int*   adj    = (int*)p;       p += (size_t)N_TOT * CAP * 4;
    short* Wt1    = (short*)p;     p += 256 * KP * 2;
    float* bb1    = (float*)p;     p += 256 * 4;
    short* Wt2    = (short*)p;     p += 256 * KP * 2;
    float* bb2    = (float*)p;

    hipMemsetAsync(cnt, 0, (size_t)N_TOT * 4, stream);
    fill_adj_kernel<<<(E_TOT + 255) / 256, 256, 0, stream>>>(edges, cnt, adj);
    conv_w_kernel<<<256, 256, 0, stream>>>(w0_1, b0_1, w1_1, b1_1, Wt1, bb1);
    conv_w_kernel<<<256, 256, 0, stream>>>(w0_2, b0_2, w1_2, b1_2, Wt2, bb2);

    // layer 0: x_A = f(normals)
    mm3_kernel<<<N_TOT / 32, 256, 0, stream>>>(normals, w0_0, b0_0, w1_0, b1_0,
                                               (short*)x0A, (short*)x1A);
    // layer 1: gather(A) -> GEMM -> B
    fused_kernel<<<N_TOT / 32, 256, 0, stream>>>(x0A, x1A, normals, cnt, adj, Wt1, bb1,
                                                 (short*)x0B, (short*)x1B);
    // layer 2: gather(B) -> GEMM -> A
    fused_kernel<<<N_TOT / 32, 256, 0, stream>>>(x0B, x1B, normals, cnt, adj, Wt2, bb2,
                                                 (short*)x0A, (short*)x1A);
    // final: gather(A) -> h (f32, overwrites dead pair B) + verts
    final_fused_kernel<<<N_TOT / 4, 256, 0, stream>>>(x0A, x1A, cnt, adj, normals, verts,
                                                      anchor_v, part_id, w_off, b_off,
                                                      hout, out_verts);
}

// Round 4
// 557.026 us; speedup vs baseline: 3.2935x; 1.0528x over previous
//
#include <hip/hip_runtime.h>

#define N_TOT 211072   // B*V = 32*6596
#define V_MESH 6596
#define E_TOT 633216   // 3*N
#define CAP 32
#define KP 184         // feats row width in bf16 (368B; only cols 0..159 read by MFMA)
#define KSTEPS 5       // 5*32 = 160 >= 131

typedef __attribute__((ext_vector_type(8))) short bf16x8;
typedef __attribute__((ext_vector_type(4))) float f32x4;
typedef __attribute__((ext_vector_type(4))) unsigned u32x4;

__constant__ float c_LIM[14] = {0.04f,0.06f,0.04f,0.04f,0.02f,0.02f,0.04f,0.04f,
                                0.03f,0.03f,0.02f,0.02f,0.01f,0.01f};

__device__ __forceinline__ unsigned f2bf(float f) {   // RNE f32->bf16
    unsigned x = __float_as_uint(f);
    return (x + 0x7fffu + ((x >> 16) & 1u)) >> 16;
}

// ---------------- adjacency build ----------------
__global__ __launch_bounds__(256) void fill_adj_kernel(const int* __restrict__ edges,
                                                       int* __restrict__ cnt,
                                                       int* __restrict__ adj) {
    int e = blockIdx.x * 256 + threadIdx.x;
    if (e >= E_TOT) return;
    int2 ed = ((const int2*)edges)[e];
    int p0 = atomicAdd(&cnt[ed.x], 1);
    if (p0 < CAP) adj[(size_t)ed.x * CAP + p0] = ed.y;
    int p1 = atomicAdd(&cnt[ed.y], 1);
    if (p1 < CAP) adj[(size_t)ed.y * CAP + p1] = ed.x;
}

// ---------------- weight conversion: Wt[256][184] bf16 (transposed, zero-padded), bb[256] ----------------
__global__ __launch_bounds__(256) void conv_w_kernel(const float* __restrict__ w0,
                                                     const float* __restrict__ b0,
                                                     const float* __restrict__ w1,
                                                     const float* __restrict__ b1,
                                                     short* __restrict__ Wt,
                                                     float* __restrict__ bb) {
    int c = blockIdx.x;          // 0..255 output col
    int k = threadIdx.x;         // 0..255
    const float* w = (c < 128) ? w0 : w1;
    int cc = c & 127;
    if (k < KP) {
        unsigned val = (k < 131) ? f2bf(w[(size_t)k * 128 + cc]) : 0u;
        Wt[(size_t)c * KP + k] = (short)val;
    }
    if (k == 0) bb[c] = (c < 128) ? b0[cc] : b1[cc];
}

// ---------------- layer 0 matmul (feats = normals, d=3) -> xc interleaved bf16 ----------------
__global__ __launch_bounds__(256) void mm3_kernel(const float* __restrict__ normals,
                                                  const float* __restrict__ w0,
                                                  const float* __restrict__ b0,
                                                  const float* __restrict__ w1,
                                                  const float* __restrict__ b1,
                                                  unsigned* __restrict__ xc) { // [N][128] dwords
    __shared__ float nL[32][3];
    int t = threadIdx.x;
    int row0 = blockIdx.x * 32;
    if (t < 96) {
        int r = t / 3, k = t - r * 3;
        nL[r][k] = normals[(size_t)(row0 + r) * 3 + k];
    }
    __syncthreads();
    int m  = (t >> 6) & 1;   // 0 -> x0 half, 1 -> x1 half
    int rh = t >> 7;
    int c2 = t & 63;         // column pair 2*c2, 2*c2+1
    const float* w = m ? w1 : w0;
    const float* b = m ? b1 : b0;
    float wA0 = w[0*128 + 2*c2],     wA1 = w[1*128 + 2*c2],     wA2 = w[2*128 + 2*c2];
    float wB0 = w[0*128 + 2*c2 + 1], wB1 = w[1*128 + 2*c2 + 1], wB2 = w[2*128 + 2*c2 + 1];
    float bA = b[2*c2], bB = b[2*c2 + 1];
    #pragma unroll
    for (int r = 0; r < 16; ++r) {
        int lr = rh * 16 + r;
        float vA = bA + nL[lr][0]*wA0 + nL[lr][1]*wA1 + nL[lr][2]*wA2;
        float vB = bB + nL[lr][0]*wB0 + nL[lr][1]*wB1 + nL[lr][2]*wB2;
        xc[(size_t)(row0 + lr) * 128 + m * 64 + c2] = f2bf(vA) | (f2bf(vB) << 16);
    }
}

// ---------------- fused: wide gather + relu -> LDS tile -> MFMA -> xc' ----------------
// 1024 threads = 16 waves; wave w owns node row0+w. Gather: 4 lane-groups of 16,
// each load fetches 4 neighbor rows (16B/lane). Inactive slots read a zero row.
__global__ __launch_bounds__(1024) void fused_kernel(const short* __restrict__ xc_in,  // [N][256]
                                                     const float* __restrict__ normals,
                                                     const int* __restrict__ cnt,
                                                     const int* __restrict__ adj,
                                                     const short* __restrict__ zb,     // 256B zeros
                                                     const short* __restrict__ Wt,     // [256][184]
                                                     const float* __restrict__ bb,     // [256]
                                                     short* __restrict__ xc_out) {     // [N][256]
    __shared__ short tileA[16 * KP];     // 5888 B gathered feats
    __shared__ short tileC[16 * 256];    // 8192 B output staging
    int tid  = threadIdx.x;
    int w    = tid >> 6;
    int lane = tid & 63;
    int g    = lane >> 4;
    int ln   = lane & 15;
    int row0 = blockIdx.x * 16;
    int i    = row0 + w;

    int deg = cnt[i]; deg = (deg > CAP) ? CAP : deg;
    int jv  = (lane < CAP) ? adj[(size_t)i * CAP + lane] : 0;
    u32x4 self = *(const u32x4*)(xc_in + (size_t)i * 256 + ln * 8);

    float a[8];
    #pragma unroll
    for (int e = 0; e < 8; ++e) a[e] = 0.f;

    int R = (deg + 3) >> 2;
    if (R > 0) {
        auto ldr = [&](int k) -> u32x4 {
            int it = 4 * k + g;
            int jj = __shfl(jv, it);
            const short* p = (it < deg) ? (xc_in + (size_t)jj * 256 + 128 + ln * 8)
                                        : (zb + ln * 8);
            return *(const u32x4*)p;
        };
        u32x4 nx = ldr(0);
        for (int k = 0; k < R; ++k) {
            u32x4 cu = nx;
            if (k + 1 < R) nx = ldr(k + 1);
            #pragma unroll
            for (int q = 0; q < 4; ++q) {
                a[2*q]   += __uint_as_float(cu[q] << 16);
                a[2*q+1] += __uint_as_float(cu[q] & 0xffff0000u);
            }
        }
    }
    #pragma unroll
    for (int e = 0; e < 8; ++e) a[e] += __shfl_xor(a[e], 16);
    #pragma unroll
    for (int e = 0; e < 8; ++e) a[e] += __shfl_xor(a[e], 32);
    #pragma unroll
    for (int q = 0; q < 4; ++q) {
        a[2*q]   += __uint_as_float(self[q] << 16);
        a[2*q+1] += __uint_as_float(self[q] & 0xffff0000u);
    }
    #pragma unroll
    for (int e = 0; e < 8; ++e) a[e] = fmaxf(a[e], 0.f);

    if (g == 0) {                       // h columns 0..127
        u32x4 dw;
        #pragma unroll
        for (int q = 0; q < 4; ++q) dw[q] = f2bf(a[2*q]) | (f2bf(a[2*q+1]) << 16);
        *(u32x4*)&tileA[w * KP + ln * 8] = dw;
    } else if (g == 1) {                // cols 128..159: normals + zero pad
        float n0 = normals[(size_t)i * 3 + 0];
        float n1 = normals[(size_t)i * 3 + 1];
        float n2 = normals[(size_t)i * 3 + 2];
        unsigned v = (ln == 0) ? (f2bf(n0) | (f2bf(n1) << 16))
                   : (ln == 1) ? f2bf(n2) : 0u;
        ((unsigned*)tileA)[w * (KP / 2) + 64 + ln] = v;
    }
    __syncthreads();

    // ---- MFMA: wave w computes 16 rows x 16 cols (col block w*16) over K=160 ----
    int cb = w * 16;
    float bv = bb[cb + ln];
    f32x4 acc = {bv, bv, bv, bv};
    #pragma unroll
    for (int kk = 0; kk < KSTEPS; ++kk) {
        bf16x8 bf = *(const bf16x8*)(Wt + (size_t)(cb + ln) * KP + kk * 32 + g * 8);
        bf16x8 af = *(const bf16x8*)(tileA + ln * KP + kk * 32 + g * 8);
        acc = __builtin_amdgcn_mfma_f32_16x16x32_bf16(af, bf, acc, 0, 0, 0);
    }
    #pragma unroll
    for (int j = 0; j < 4; ++j)
        tileC[(g * 4 + j) * 256 + cb + ln] = (short)f2bf(acc[j]);
    __syncthreads();

    // ---- coalesced row writeback: wave w stores row row0+w (512B) ----
    ushort4 v = *(const ushort4*)&tileC[w * 256 + lane * 4];
    *(ushort4*)(xc_out + (size_t)(row0 + w) * 256 + lane * 4) = v;
}

// ---------------- final: wide gather + relu -> h (f32) + deform + vertex update ----------------
__global__ __launch_bounds__(256) void final_fused_kernel(const short* __restrict__ xc_in,
                                                          const int* __restrict__ cnt,
                                                          const int* __restrict__ adj,
                                                          const short* __restrict__ zb,
                                                          const float* __restrict__ normals,
                                                          const float* __restrict__ verts,
                                                          const float* __restrict__ anchor_v,
                                                          const int* __restrict__ part_id,
                                                          const float* __restrict__ w_off,
                                                          const float* __restrict__ b_off,
                                                          float* __restrict__ hout,
                                                          float* __restrict__ out_verts) {
    __shared__ float wo[131 * 3];
    for (int t = threadIdx.x; t < 131 * 3; t += 256) wo[t] = w_off[t];
    __syncthreads();
    int tid  = threadIdx.x;
    int w    = tid >> 6;
    int lane = tid & 63;
    int g    = lane >> 4;
    int ln   = lane & 15;
    int i    = blockIdx.x * 4 + w;

    int deg = cnt[i]; deg = (deg > CAP) ? CAP : deg;
    int jv  = (lane < CAP) ? adj[(size_t)i * CAP + lane] : 0;
    u32x4 self = *(const u32x4*)(xc_in + (size_t)i * 256 + ln * 8);

    float a[8];
    #pragma unroll
    for (int e = 0; e < 8; ++e) a[e] = 0.f;
    int R = (deg + 3) >> 2;
    if (R > 0) {
        auto ldr = [&](int k) -> u32x4 {
            int it = 4 * k + g;
            int jj = __shfl(jv, it);
            const short* p = (it < deg) ? (xc_in + (size_t)jj * 256 + 128 + ln * 8)
                                        : (zb + ln * 8);
            return *(const u32x4*)p;
        };
        u32x4 nx = ldr(0);
        for (int k = 0; k < R; ++k) {
            u32x4 cu = nx;
            if (k + 1 < R) nx = ldr(k + 1);
            #pragma unroll
            for (int q = 0; q < 4; ++q) {
                a[2*q]   += __uint_as_float(cu[q] << 16);
                a[2*q+1] += __uint_as_float(cu[q] & 0xffff0000u);
            }
        }
    }
    #pragma unroll
    for (int e = 0; e < 8; ++e) a[e] += __shfl_xor(a[e], 16);
    #pragma unroll
    for (int e = 0; e < 8; ++e) a[e] += __shfl_xor(a[e], 32);
    #pragma unroll
    for (int q = 0; q < 4; ++q) {
        a[2*q]   += __uint_as_float(self[q] << 16);
        a[2*q+1] += __uint_as_float(self[q] & 0xffff0000u);
    }
    #pragma unroll
    for (int e = 0; e < 8; ++e) a[e] = fmaxf(a[e], 0.f);

    // h store: group g writes float pair (cols ln*8+2g, +1) -> full 512B row across wave
    float2 hv; hv.x = a[g * 2]; hv.y = a[g * 2 + 1];
    ((float2*)(hout + (size_t)i * 128))[ln * 4 + g] = hv;

    // offset head: partial dot over this lane's 8 cols, reduce over 16-lane group
    float s0 = 0.f, s1 = 0.f, s2 = 0.f;
    #pragma unroll
    for (int e = 0; e < 8; ++e) {
        int c = ln * 8 + e;
        s0 += a[e] * wo[c * 3 + 0];
        s1 += a[e] * wo[c * 3 + 1];
        s2 += a[e] * wo[c * 3 + 2];
    }
    #pragma unroll
    for (int d = 1; d < 16; d <<= 1) {
        s0 += __shfl_xor(s0, d);
        s1 += __shfl_xor(s1, d);
        s2 += __shfl_xor(s2, d);
    }
    if (lane < 3) {
        int v = i % V_MESH;
        float n0 = normals[(size_t)i * 3 + 0];
        float n1 = normals[(size_t)i * 3 + 1];
        float n2 = normals[(size_t)i * 3 + 2];
        float s = (lane == 0) ? s0 : (lane == 1) ? s1 : s2;
        s += n0 * wo[128 * 3 + lane] + n1 * wo[129 * 3 + lane] + n2 * wo[130 * 3 + lane];
        s += b_off[lane];
        float dd = tanhf(s);
        float lim = c_LIM[part_id[v]];
        dd = fminf(fmaxf(dd, -lim), lim);
        out_verts[(size_t)i * 3 + lane] =
            verts[(size_t)i * 3 + lane] + dd * anchor_v[(size_t)v * 3 + lane];
    }
}

extern "C" void kernel_launch(void* const* d_in, const int* in_sizes, int n_in,
                              void* d_out, int out_size, void* d_ws, size_t ws_size,
                              hipStream_t stream) {
    const float* verts    = (const float*)d_in[0];
    const float* normals  = (const float*)d_in[1];
    const float* anchor_v = (const float*)d_in[2];
    const int*   edges    = (const int*)d_in[3];
    const int*   part_id  = (const int*)d_in[4];
    const float* w0_0 = (const float*)d_in[5];
    const float* b0_0 = (const float*)d_in[6];
    const float* w1_0 = (const float*)d_in[7];
    const float* b1_0 = (const float*)d_in[8];
    const float* w0_1 = (const float*)d_in[9];
    const float* b0_1 = (const float*)d_in[10];
    const float* w1_1 = (const float*)d_in[11];
    const float* b1_1 = (const float*)d_in[12];
    const float* w0_2 = (const float*)d_in[13];
    const float* b0_2 = (const float*)d_in[14];
    const float* w1_2 = (const float*)d_in[15];
    const float* b1_2 = (const float*)d_in[16];
    const float* w_off = (const float*)d_in[17];
    const float* b_off = (const float*)d_in[18];

    float* out_verts = (float*)d_out;
    float* hout = (float*)d_out + (size_t)3 * N_TOT;   // final h (f32), 108 MB

    // pair B aliases the (dead until final) h region: [N][256] bf16 = 108 MB
    short* xcB = (short*)hout;

    char* p = (char*)d_ws;
    short* xcA = (short*)p;   p += (size_t)N_TOT * 256 * 2;
    int*   cnt = (int*)p;     p += (size_t)N_TOT * 4;
    int*   adj = (int*)p;     p += (size_t)N_TOT * CAP * 4;
    short* Wt1 = (short*)p;   p += 256 * KP * 2;
    float* bb1 = (float*)p;   p += 256 * 4;
    short* Wt2 = (short*)p;   p += 256 * KP * 2;
    float* bb2 = (float*)p;   p += 256 * 4;
    short* zb  = (short*)p;   p += 512;

    hipMemsetAsync(cnt, 0, (size_t)N_TOT * 4, stream);
    hipMemsetAsync((void*)zb, 0, 512, stream);
    fill_adj_kernel<<<(E_TOT + 255) / 256, 256, 0, stream>>>(edges, cnt, adj);
    conv_w_kernel<<<256, 256, 0, stream>>>(w0_1, b0_1, w1_1, b1_1, Wt1, bb1);
    conv_w_kernel<<<256, 256, 0, stream>>>(w0_2, b0_2, w1_2, b1_2, Wt2, bb2);

    // layer 0
    mm3_kernel<<<N_TOT / 32, 256, 0, stream>>>(normals, w0_0, b0_0, w1_0, b1_0,
                                               (unsigned*)xcA);
    // layer 1: gather(A) -> GEMM -> B
    fused_kernel<<<N_TOT / 16, 1024, 0, stream>>>(xcA, normals, cnt, adj, zb, Wt1, bb1, xcB);
    // layer 2: gather(B) -> GEMM -> A
    fused_kernel<<<N_TOT / 16, 1024, 0, stream>>>(xcB, normals, cnt, adj, zb, Wt2, bb2, xcA);
    // final: gather(A) -> h + verts (h overwrites dead xcB region)
    final_fused_kernel<<<N_TOT / 4, 256, 0, stream>>>(xcA, cnt, adj, zb, normals, verts,
                                                      anchor_v, part_id, w_off, b_off,
                                                      hout, out_verts);
}

// Round 5
// 530.204 us; speedup vs baseline: 3.4601x; 1.0506x over previous
//
#include <hip/hip_runtime.h>

#define N_TOT 211072   // B*V = 32*6596
#define V_MESH 6596
#define E_TOT 633216   // 3*N
#define CAP 32
#define KP 184         // feats row width in bf16 (368B; MFMA reads cols 0..159)
#define KSTEPS 5       // 5*32 = 160 >= 131

typedef __attribute__((ext_vector_type(8))) short bf16x8;
typedef __attribute__((ext_vector_type(4))) float f32x4;

__constant__ float c_LIM[14] = {0.04f,0.06f,0.04f,0.04f,0.02f,0.02f,0.04f,0.04f,
                                0.03f,0.03f,0.02f,0.02f,0.01f,0.01f};

__device__ __forceinline__ unsigned f2bf(float f) {   // RNE f32->bf16
    unsigned x = __float_as_uint(f);
    return (x + 0x7fffu + ((x >> 16) & 1u)) >> 16;
}
__device__ __forceinline__ float bflo(unsigned u) { return __uint_as_float(u << 16); }
__device__ __forceinline__ float bfhi(unsigned u) { return __uint_as_float(u & 0xffff0000u); }

// ---------------- adjacency build ----------------
__global__ __launch_bounds__(256) void fill_adj_kernel(const int* __restrict__ edges,
                                                       int* __restrict__ cnt,
                                                       int* __restrict__ adj) {
    int e = blockIdx.x * 256 + threadIdx.x;
    if (e >= E_TOT) return;
    int2 ed = ((const int2*)edges)[e];
    int p0 = atomicAdd(&cnt[ed.x], 1);
    if (p0 < CAP) adj[(size_t)ed.x * CAP + p0] = ed.y;
    int p1 = atomicAdd(&cnt[ed.y], 1);
    if (p1 < CAP) adj[(size_t)ed.y * CAP + p1] = ed.x;
}

// ---------------- weight conversion: Wt[256][184] bf16 (transposed, zero-padded), bb[256] ----------------
__global__ __launch_bounds__(256) void conv_w_kernel(const float* __restrict__ w0,
                                                     const float* __restrict__ b0,
                                                     const float* __restrict__ w1,
                                                     const float* __restrict__ b1,
                                                     short* __restrict__ Wt,
                                                     float* __restrict__ bb) {
    int c = blockIdx.x;          // 0..255 output col
    int k = threadIdx.x;         // 0..255
    const float* w = (c < 128) ? w0 : w1;
    int cc = c & 127;
    if (k < KP) {
        unsigned val = (k < 131) ? f2bf(w[(size_t)k * 128 + cc]) : 0u;
        Wt[(size_t)c * KP + k] = (short)val;
    }
    if (k == 0) bb[c] = (c < 128) ? b0[cc] : b1[cc];
}

// ---------------- layer 0 matmul (feats = normals, d=3) -> xc interleaved bf16 ----------------
__global__ __launch_bounds__(256) void mm3_kernel(const float* __restrict__ normals,
                                                  const float* __restrict__ w0,
                                                  const float* __restrict__ b0,
                                                  const float* __restrict__ w1,
                                                  const float* __restrict__ b1,
                                                  unsigned* __restrict__ xc) { // [N][128] dwords
    __shared__ float nL[32][3];
    int t = threadIdx.x;
    int row0 = blockIdx.x * 32;
    if (t < 96) {
        int r = t / 3, k = t - r * 3;
        nL[r][k] = normals[(size_t)(row0 + r) * 3 + k];
    }
    __syncthreads();
    int m  = (t >> 6) & 1;   // 0 -> x0 half, 1 -> x1 half
    int rh = t >> 7;
    int c2 = t & 63;         // column pair 2*c2, 2*c2+1
    const float* w = m ? w1 : w0;
    const float* b = m ? b1 : b0;
    float wA0 = w[0*128 + 2*c2],     wA1 = w[1*128 + 2*c2],     wA2 = w[2*128 + 2*c2];
    float wB0 = w[0*128 + 2*c2 + 1], wB1 = w[1*128 + 2*c2 + 1], wB2 = w[2*128 + 2*c2 + 1];
    float bA = b[2*c2], bB = b[2*c2 + 1];
    #pragma unroll
    for (int r = 0; r < 16; ++r) {
        int lr = rh * 16 + r;
        float vA = bA + nL[lr][0]*wA0 + nL[lr][1]*wA1 + nL[lr][2]*wA2;
        float vB = bB + nL[lr][0]*wB0 + nL[lr][1]*wB1 + nL[lr][2]*wB2;
        xc[(size_t)(row0 + lr) * 128 + m * 64 + c2] = f2bf(vA) | (f2bf(vB) << 16);
    }
}

// ---------------- fused: lane-per-dword gather + relu -> LDS tile -> MFMA -> xc' ----------------
// 1024 threads = 16 waves; wave w owns node row0+w. Lane l owns cols (2l, 2l+1):
// each neighbor is ONE coalesced 256B dword-load with scalar (readlane) base.
__global__ __launch_bounds__(1024) void fused_kernel(const unsigned* __restrict__ xc_in, // [N][128] dw
                                                     const float* __restrict__ normals,
                                                     const int* __restrict__ cnt,
                                                     const int* __restrict__ adj,
                                                     const short* __restrict__ Wt,      // [256][184]
                                                     const float* __restrict__ bb,      // [256]
                                                     unsigned* __restrict__ xc_out) {   // [N][128] dw
    __shared__ short tileA[16 * KP];     // 5888 B gathered feats
    __shared__ short tileC[16 * 256];    // 8192 B output staging (XOR-swizzled)
    int tid  = threadIdx.x;
    int w    = tid >> 6;
    int lane = tid & 63;
    int g    = lane >> 4;
    int ln   = lane & 15;
    int row0 = blockIdx.x * 16;
    int i    = row0 + w;

    // ---- early independent loads ----
    int deg = cnt[i]; deg = (deg > CAP) ? CAP : deg;
    deg = __builtin_amdgcn_readfirstlane(deg);
    int jv = (lane < CAP) ? adj[(size_t)i * CAP + lane] : 0;
    unsigned selfu = xc_in[(size_t)i * 128 + lane];          // x0 dword (cols 2l,2l+1)
    float nv = (lane < 3) ? normals[(size_t)i * 3 + lane] : 0.f;
    int cb = w * 16;
    float bv = bb[cb + ln];
    bf16x8 bfrag[KSTEPS];
    #pragma unroll
    for (int kk = 0; kk < KSTEPS; ++kk)
        bfrag[kk] = *(const bf16x8*)(Wt + (size_t)(cb + ln) * KP + kk * 32 + g * 8);

    // ---- gather: one dword-load per neighbor, dual accumulators ----
    float a0 = bflo(selfu), a1 = bfhi(selfu);
    float c0a = 0.f, c1a = 0.f;
    const unsigned* x1b = xc_in + 64 + lane;   // + jj*128
    int k = 0;
    for (; k + 1 < deg; k += 2) {
        int j0 = __builtin_amdgcn_readlane(jv, k);
        int j1 = __builtin_amdgcn_readlane(jv, k + 1);
        unsigned u0 = x1b[(size_t)j0 * 128];
        unsigned u1 = x1b[(size_t)j1 * 128];
        a0  += bflo(u0); a1  += bfhi(u0);
        c0a += bflo(u1); c1a += bfhi(u1);
    }
    if (k < deg) {
        int j0 = __builtin_amdgcn_readlane(jv, k);
        unsigned u0 = x1b[(size_t)j0 * 128];
        a0 += bflo(u0); a1 += bfhi(u0);
    }
    a0 = fmaxf(a0 + c0a, 0.f);
    a1 = fmaxf(a1 + c1a, 0.f);

    // ---- write tile row: dwords 0..63 = h, 64..79 = normals + pad ----
    ((unsigned*)tileA)[w * (KP / 2) + lane] = f2bf(a0) | (f2bf(a1) << 16);
    unsigned nb = f2bf(nv);
    unsigned nb0 = __shfl((int)nb, 0), nb1 = __shfl((int)nb, 1), nb2 = __shfl((int)nb, 2);
    if (lane < 16) {
        unsigned v = (lane == 0) ? (nb0 | (nb1 << 16)) : (lane == 1) ? nb2 : 0u;
        ((unsigned*)tileA)[w * (KP / 2) + 64 + lane] = v;
    }
    __syncthreads();

    // ---- MFMA: wave w computes 16 rows x 16 cols (col block w*16) over K=160 ----
    f32x4 acc = {bv, bv, bv, bv};
    #pragma unroll
    for (int kk = 0; kk < KSTEPS; ++kk) {
        bf16x8 af = *(const bf16x8*)(tileA + ln * KP + kk * 32 + g * 8);
        acc = __builtin_amdgcn_mfma_f32_16x16x32_bf16(af, bfrag[kk], acc, 0, 0, 0);
    }
    #pragma unroll
    for (int j = 0; j < 4; ++j) {
        int row = g * 4 + j;
        tileC[row * 256 + ((cb + ln) ^ ((row & 12) << 2))] = (short)f2bf(acc[j]);
    }
    __syncthreads();

    // ---- coalesced row writeback (un-swizzle with row-known key) ----
    int col4 = (lane * 4) ^ ((w & 12) << 2);
    ushort4 v4 = *(const ushort4*)&tileC[w * 256 + col4];
    ushort4* dst = (ushort4*)((short*)xc_out + (size_t)(row0 + w) * 256);
    dst[lane] = make_ushort4(v4.x, v4.y, v4.z, v4.w);
}

// ---------------- final: lane-per-dword gather + relu -> h (f32) + deform + vertex update ----------------
__global__ __launch_bounds__(256) void final_fused_kernel(const unsigned* __restrict__ xc_in,
                                                          const int* __restrict__ cnt,
                                                          const int* __restrict__ adj,
                                                          const float* __restrict__ normals,
                                                          const float* __restrict__ verts,
                                                          const float* __restrict__ anchor_v,
                                                          const int* __restrict__ part_id,
                                                          const float* __restrict__ w_off,
                                                          const float* __restrict__ b_off,
                                                          float* __restrict__ hout,
                                                          float* __restrict__ out_verts) {
    __shared__ float wo[131 * 3];
    for (int t = threadIdx.x; t < 131 * 3; t += 256) wo[t] = w_off[t];
    __syncthreads();
    int tid  = threadIdx.x;
    int w    = tid >> 6;
    int lane = tid & 63;
    int i    = blockIdx.x * 4 + w;

    int deg = cnt[i]; deg = (deg > CAP) ? CAP : deg;
    deg = __builtin_amdgcn_readfirstlane(deg);
    int jv = (lane < CAP) ? adj[(size_t)i * CAP + lane] : 0;
    unsigned selfu = xc_in[(size_t)i * 128 + lane];

    float a0 = bflo(selfu), a1 = bfhi(selfu);
    float c0a = 0.f, c1a = 0.f;
    const unsigned* x1b = xc_in + 64 + lane;
    int k = 0;
    for (; k + 1 < deg; k += 2) {
        int j0 = __builtin_amdgcn_readlane(jv, k);
        int j1 = __builtin_amdgcn_readlane(jv, k + 1);
        unsigned u0 = x1b[(size_t)j0 * 128];
        unsigned u1 = x1b[(size_t)j1 * 128];
        a0  += bflo(u0); a1  += bfhi(u0);
        c0a += bflo(u1); c1a += bfhi(u1);
    }
    if (k < deg) {
        int j0 = __builtin_amdgcn_readlane(jv, k);
        unsigned u0 = x1b[(size_t)j0 * 128];
        a0 += bflo(u0); a1 += bfhi(u0);
    }
    a0 = fmaxf(a0 + c0a, 0.f);
    a1 = fmaxf(a1 + c1a, 0.f);

    // h store: lane l writes cols (2l, 2l+1) -> full 512B row per wave
    float2 hv; hv.x = a0; hv.y = a1;
    ((float2*)(hout + (size_t)i * 128))[lane] = hv;

    // offset head: partial dot over this lane's 2 cols, full-wave reduce
    int cA = 2 * lane, cB = 2 * lane + 1;
    float s0 = a0 * wo[cA * 3 + 0] + a1 * wo[cB * 3 + 0];
    float s1 = a0 * wo[cA * 3 + 1] + a1 * wo[cB * 3 + 1];
    float s2 = a0 * wo[cA * 3 + 2] + a1 * wo[cB * 3 + 2];
    #pragma unroll
    for (int d = 32; d; d >>= 1) {
        s0 += __shfl_xor(s0, d);
        s1 += __shfl_xor(s1, d);
        s2 += __shfl_xor(s2, d);
    }
    if (lane < 3) {
        int v = i % V_MESH;
        float n0 = normals[(size_t)i * 3 + 0];
        float n1 = normals[(size_t)i * 3 + 1];
        float n2 = normals[(size_t)i * 3 + 2];
        float s = (lane == 0) ? s0 : (lane == 1) ? s1 : s2;
        s += n0 * wo[128 * 3 + lane] + n1 * wo[129 * 3 + lane] + n2 * wo[130 * 3 + lane];
        s += b_off[lane];
        float dd = tanhf(s);
        float lim = c_LIM[part_id[v]];
        dd = fminf(fmaxf(dd, -lim), lim);
        out_verts[(size_t)i * 3 + lane] =
            verts[(size_t)i * 3 + lane] + dd * anchor_v[(size_t)v * 3 + lane];
    }
}

extern "C" void kernel_launch(void* const* d_in, const int* in_sizes, int n_in,
                              void* d_out, int out_size, void* d_ws, size_t ws_size,
                              hipStream_t stream) {
    const float* verts    = (const float*)d_in[0];
    const float* normals  = (const float*)d_in[1];
    const float* anchor_v = (const float*)d_in[2];
    const int*   edges    = (const int*)d_in[3];
    const int*   part_id  = (const int*)d_in[4];
    const float* w0_0 = (const float*)d_in[5];
    const float* b0_0 = (const float*)d_in[6];
    const float* w1_0 = (const float*)d_in[7];
    const float* b1_0 = (const float*)d_in[8];
    const float* w0_1 = (const float*)d_in[9];
    const float* b0_1 = (const float*)d_in[10];
    const float* w1_1 = (const float*)d_in[11];
    const float* b1_1 = (const float*)d_in[12];
    const float* w0_2 = (const float*)d_in[13];
    const float* b0_2 = (const float*)d_in[14];
    const float* w1_2 = (const float*)d_in[15];
    const float* b1_2 = (const float*)d_in[16];
    const float* w_off = (const float*)d_in[17];
    const float* b_off = (const float*)d_in[18];

    float* out_verts = (float*)d_out;
    float* hout = (float*)d_out + (size_t)3 * N_TOT;   // final h (f32), 108 MB

    // pair B aliases the (dead until final) h region: [N][128] dwords = 108 MB
    unsigned* xcB = (unsigned*)hout;

    char* p = (char*)d_ws;
    unsigned* xcA = (unsigned*)p;  p += (size_t)N_TOT * 128 * 4;
    int*   cnt = (int*)p;          p += (size_t)N_TOT * 4;
    int*   adj = (int*)p;          p += (size_t)N_TOT * CAP * 4;
    short* Wt1 = (short*)p;        p += 256 * KP * 2;
    float* bb1 = (float*)p;        p += 256 * 4;
    short* Wt2 = (short*)p;        p += 256 * KP * 2;
    float* bb2 = (float*)p;

    hipMemsetAsync(cnt, 0, (size_t)N_TOT * 4, stream);
    fill_adj_kernel<<<(E_TOT + 255) / 256, 256, 0, stream>>>(edges, cnt, adj);
    conv_w_kernel<<<256, 256, 0, stream>>>(w0_1, b0_1, w1_1, b1_1, Wt1, bb1);
    conv_w_kernel<<<256, 256, 0, stream>>>(w0_2, b0_2, w1_2, b1_2, Wt2, bb2);

    // layer 0
    mm3_kernel<<<N_TOT / 32, 256, 0, stream>>>(normals, w0_0, b0_0, w1_0, b1_0, xcA);
    // layer 1: gather(A) -> GEMM -> B
    fused_kernel<<<N_TOT / 16, 1024, 0, stream>>>(xcA, normals, cnt, adj, Wt1, bb1, xcB);
    // layer 2: gather(B) -> GEMM -> A
    fused_kernel<<<N_TOT / 16, 1024, 0, stream>>>(xcB, normals, cnt, adj, Wt2, bb2, xcA);
    // final: gather(A) -> h + verts (h overwrites dead xcB region)
    final_fused_kernel<<<N_TOT / 4, 256, 0, stream>>>(xcA, cnt, adj, normals, verts,
                                                      anchor_v, part_id, w_off, b_off,
                                                      hout, out_verts);
}

// Round 6
// 466.690 us; speedup vs baseline: 3.9310x; 1.1361x over previous
//
#include <hip/hip_runtime.h>

#define N_TOT 211072   // B*V = 32*6596
#define V_MESH 6596
#define E_TOT 633216   // 3*N
#define CAP 32
#define KP 184         // feats row width in bf16 (368B; MFMA reads cols 0..159)
#define KSTEPS 5       // 5*32 = 160 >= 131

typedef __attribute__((ext_vector_type(8))) short bf16x8;
typedef __attribute__((ext_vector_type(4))) float f32x4;

__constant__ float c_LIM[14] = {0.04f,0.06f,0.04f,0.04f,0.02f,0.02f,0.04f,0.04f,
                                0.03f,0.03f,0.02f,0.02f,0.01f,0.01f};

__device__ __forceinline__ unsigned f2bf(float f) {   // RNE f32->bf16
    unsigned x = __float_as_uint(f);
    return (x + 0x7fffu + ((x >> 16) & 1u)) >> 16;
}
__device__ __forceinline__ float bflo(unsigned u) { return __uint_as_float(u << 16); }
__device__ __forceinline__ float bfhi(unsigned u) { return __uint_as_float(u & 0xffff0000u); }

// ---------------- adjacency init (sentinel = N_TOT -> zero row) ----------------
__global__ __launch_bounds__(256) void init_adj_kernel(int4* __restrict__ adj4) {
    size_t idx = (size_t)blockIdx.x * 256 + threadIdx.x;   // grid sized exactly
    adj4[idx] = make_int4(N_TOT, N_TOT, N_TOT, N_TOT);
}

// ---------------- adjacency build ----------------
__global__ __launch_bounds__(256) void fill_adj_kernel(const int* __restrict__ edges,
                                                       int* __restrict__ cnt,
                                                       int* __restrict__ adj) {
    int e = blockIdx.x * 256 + threadIdx.x;
    if (e >= E_TOT) return;
    int2 ed = ((const int2*)edges)[e];
    int p0 = atomicAdd(&cnt[ed.x], 1);
    if (p0 < CAP) adj[(size_t)ed.x * CAP + p0] = ed.y;
    int p1 = atomicAdd(&cnt[ed.y], 1);
    if (p1 < CAP) adj[(size_t)ed.y * CAP + p1] = ed.x;
}

// ---------------- weight conversion: Wt[256][184] bf16 (transposed, zero-padded), bb[256] ----------------
__global__ __launch_bounds__(256) void conv_w_kernel(const float* __restrict__ w0,
                                                     const float* __restrict__ b0,
                                                     const float* __restrict__ w1,
                                                     const float* __restrict__ b1,
                                                     short* __restrict__ Wt,
                                                     float* __restrict__ bb) {
    int c = blockIdx.x;          // 0..255 output col
    int k = threadIdx.x;         // 0..255
    const float* w = (c < 128) ? w0 : w1;
    int cc = c & 127;
    if (k < KP) {
        unsigned val = (k < 131) ? f2bf(w[(size_t)k * 128 + cc]) : 0u;
        Wt[(size_t)c * KP + k] = (short)val;
    }
    if (k == 0) bb[c] = (c < 128) ? b0[cc] : b1[cc];
}

// ---------------- layer 0 matmul (feats = normals, d=3) -> xc interleaved bf16 ----------------
__global__ __launch_bounds__(256) void mm3_kernel(const float* __restrict__ normals,
                                                  const float* __restrict__ w0,
                                                  const float* __restrict__ b0,
                                                  const float* __restrict__ w1,
                                                  const float* __restrict__ b1,
                                                  unsigned* __restrict__ xc) { // [N][128] dwords
    __shared__ float nL[32][3];
    int t = threadIdx.x;
    int row0 = blockIdx.x * 32;
    if (t < 96) {
        int r = t / 3, k = t - r * 3;
        nL[r][k] = normals[(size_t)(row0 + r) * 3 + k];
    }
    __syncthreads();
    int m  = (t >> 6) & 1;   // 0 -> x0 half, 1 -> x1 half
    int rh = t >> 7;
    int c2 = t & 63;         // column pair 2*c2, 2*c2+1
    const float* w = m ? w1 : w0;
    const float* b = m ? b1 : b0;
    float wA0 = w[0*128 + 2*c2],     wA1 = w[1*128 + 2*c2],     wA2 = w[2*128 + 2*c2];
    float wB0 = w[0*128 + 2*c2 + 1], wB1 = w[1*128 + 2*c2 + 1], wB2 = w[2*128 + 2*c2 + 1];
    float bA = b[2*c2], bB = b[2*c2 + 1];
    #pragma unroll
    for (int r = 0; r < 16; ++r) {
        int lr = rh * 16 + r;
        float vA = bA + nL[lr][0]*wA0 + nL[lr][1]*wA1 + nL[lr][2]*wA2;
        float vB = bB + nL[lr][0]*wB0 + nL[lr][1]*wB1 + nL[lr][2]*wB2;
        xc[(size_t)(row0 + lr) * 128 + m * 64 + c2] = f2bf(vA) | (f2bf(vB) << 16);
    }
}

// ---------------- fused: 8-deep branch-free gather + relu -> LDS tile -> MFMA -> xc' ----------------
// 1024 threads = 16 waves; wave w owns node row0+w. Lane l owns cols (2l, 2l+1).
// adj is padded with sentinel N_TOT -> zero row; first 8 gathers issue unconditionally.
__global__ __launch_bounds__(1024, 8) void fused_kernel(const unsigned* __restrict__ xc_in, // [N+1][128]
                                                        const float* __restrict__ normals,
                                                        const int* __restrict__ cnt,
                                                        const int* __restrict__ adj,
                                                        const short* __restrict__ Wt,      // [256][184]
                                                        const float* __restrict__ bb,      // [256]
                                                        unsigned* __restrict__ xc_out) {   // [N+1][128]
    __shared__ short tileA[16 * KP];     // 5888 B gathered feats
    __shared__ short tileC[16 * 256];    // 8192 B output staging (pair-packed, swizzled)
    int tid  = threadIdx.x;
    int w    = tid >> 6;
    int lane = tid & 63;
    int g    = lane >> 4;
    int ln   = lane & 15;
    int row0 = blockIdx.x * 16;
    int i    = row0 + w;

    // ---- early independent loads ----
    int deg0 = cnt[i];
    int jv = (lane < CAP) ? adj[(size_t)i * CAP + lane] : (int)N_TOT;
    unsigned selfu = xc_in[(size_t)i * 128 + lane];          // x0 dword (cols 2l,2l+1)
    float nv = (lane < 3) ? normals[(size_t)i * 3 + lane] : 0.f;
    int cb = w * 16;
    float bv = bb[cb + ln];
    bf16x8 bfrag[KSTEPS];
    #pragma unroll
    for (int kk = 0; kk < KSTEPS; ++kk)
        bfrag[kk] = *(const bf16x8*)(Wt + (size_t)(cb + ln) * KP + kk * 32 + g * 8);

    // ---- round 0: 8 unconditional gathers, all in flight ----
    const unsigned* x1b = xc_in + 64 + lane;   // + jj*128
    unsigned u[8];
    #pragma unroll
    for (int q = 0; q < 8; ++q) {
        int j = __builtin_amdgcn_readlane(jv, q);
        u[q] = x1b[(size_t)j * 128];
    }
    float a0 = bflo(selfu), a1 = bfhi(selfu);
    float d0 = 0.f, d1 = 0.f;
    #pragma unroll
    for (int q = 0; q < 8; q += 2) {
        a0 += bflo(u[q]);     a1 += bfhi(u[q]);
        d0 += bflo(u[q + 1]); d1 += bfhi(u[q + 1]);
    }
    // ---- extra rounds (deg > 8, uncommon) ----
    int deg = (deg0 > CAP) ? CAP : deg0;
    deg = __builtin_amdgcn_readfirstlane(deg);
    for (int base = 8; base < deg; base += 8) {
        unsigned v[8];
        #pragma unroll
        for (int q = 0; q < 8; ++q) {
            int j = __builtin_amdgcn_readlane(jv, base + q);
            v[q] = x1b[(size_t)j * 128];
        }
        #pragma unroll
        for (int q = 0; q < 8; q += 2) {
            a0 += bflo(v[q]);     a1 += bfhi(v[q]);
            d0 += bflo(v[q + 1]); d1 += bfhi(v[q + 1]);
        }
    }
    a0 = fmaxf(a0 + d0, 0.f);
    a1 = fmaxf(a1 + d1, 0.f);

    // ---- write tile row: dwords 0..63 = h, 64..79 = normals + pad ----
    ((unsigned*)tileA)[w * (KP / 2) + lane] = f2bf(a0) | (f2bf(a1) << 16);
    unsigned nb = f2bf(nv);
    unsigned nb0 = __shfl((int)nb, 0), nb1 = __shfl((int)nb, 1), nb2 = __shfl((int)nb, 2);
    if (lane < 16) {
        unsigned v = (lane == 0) ? (nb0 | (nb1 << 16)) : (lane == 1) ? nb2 : 0u;
        ((unsigned*)tileA)[w * (KP / 2) + 64 + lane] = v;
    }
    __syncthreads();

    // ---- MFMA: wave w computes 16 rows x 16 cols (col block w*16) over K=160 ----
    f32x4 acc = {bv, bv, bv, bv};
    #pragma unroll
    for (int kk = 0; kk < KSTEPS; ++kk) {
        bf16x8 af = *(const bf16x8*)(tileA + ln * KP + kk * 32 + g * 8);
        acc = __builtin_amdgcn_mfma_f32_16x16x32_bf16(af, bfrag[kk], acc, 0, 0, 0);
    }
    // pair-pack cols via shfl, dword stores, XOR-swizzle by lane-group -> conflict-free
    #pragma unroll
    for (int j = 0; j < 4; ++j) {
        float po = __shfl_xor(acc[j], 1);
        if (!(ln & 1)) {
            unsigned pk = f2bf(acc[j]) | (f2bf(po) << 16);
            int d = w * 8 + (ln >> 1);           // true dword within row
            int row = g * 4 + j;
            ((unsigned*)tileC)[row * 128 + (d ^ (g << 3))] = pk;
        }
    }
    __syncthreads();

    // ---- coalesced row writeback (inverse swizzle; key = row's writer-group) ----
    int key = (w >> 2) << 3;
    ushort4 v4 = *(const ushort4*)&((unsigned*)tileC)[w * 128 + ((2 * lane) ^ key)];
    ((ushort4*)(xc_out + (size_t)(row0 + w) * 128))[lane] = v4;
}

// ---------------- final: 8-deep gather + relu -> h (f32) + deform + vertex update ----------------
__global__ __launch_bounds__(256) void final_fused_kernel(const unsigned* __restrict__ xc_in,
                                                          const int* __restrict__ cnt,
                                                          const int* __restrict__ adj,
                                                          const float* __restrict__ normals,
                                                          const float* __restrict__ verts,
                                                          const float* __restrict__ anchor_v,
                                                          const int* __restrict__ part_id,
                                                          const float* __restrict__ w_off,
                                                          const float* __restrict__ b_off,
                                                          float* __restrict__ hout,
                                                          float* __restrict__ out_verts) {
    __shared__ float wo[131 * 3];
    for (int t = threadIdx.x; t < 131 * 3; t += 256) wo[t] = w_off[t];
    __syncthreads();
    int tid  = threadIdx.x;
    int w    = tid >> 6;
    int lane = tid & 63;
    int i    = blockIdx.x * 4 + w;

    int deg0 = cnt[i];
    int jv = (lane < CAP) ? adj[(size_t)i * CAP + lane] : (int)N_TOT;
    unsigned selfu = xc_in[(size_t)i * 128 + lane];

    const unsigned* x1b = xc_in + 64 + lane;
    unsigned u[8];
    #pragma unroll
    for (int q = 0; q < 8; ++q) {
        int j = __builtin_amdgcn_readlane(jv, q);
        u[q] = x1b[(size_t)j * 128];
    }
    float a0 = bflo(selfu), a1 = bfhi(selfu);
    float d0 = 0.f, d1 = 0.f;
    #pragma unroll
    for (int q = 0; q < 8; q += 2) {
        a0 += bflo(u[q]);     a1 += bfhi(u[q]);
        d0 += bflo(u[q + 1]); d1 += bfhi(u[q + 1]);
    }
    int deg = (deg0 > CAP) ? CAP : deg0;
    deg = __builtin_amdgcn_readfirstlane(deg);
    for (int base = 8; base < deg; base += 8) {
        unsigned v[8];
        #pragma unroll
        for (int q = 0; q < 8; ++q) {
            int j = __builtin_amdgcn_readlane(jv, base + q);
            v[q] = x1b[(size_t)j * 128];
        }
        #pragma unroll
        for (int q = 0; q < 8; q += 2) {
            a0 += bflo(v[q]);     a1 += bfhi(v[q]);
            d0 += bflo(v[q + 1]); d1 += bfhi(v[q + 1]);
        }
    }
    a0 = fmaxf(a0 + d0, 0.f);
    a1 = fmaxf(a1 + d1, 0.f);

    // h store: lane l writes cols (2l, 2l+1) -> full 512B row per wave
    float2 hv; hv.x = a0; hv.y = a1;
    ((float2*)(hout + (size_t)i * 128))[lane] = hv;

    // offset head: partial dot over this lane's 2 cols, full-wave reduce
    int cA = 2 * lane, cB = 2 * lane + 1;
    float s0 = a0 * wo[cA * 3 + 0] + a1 * wo[cB * 3 + 0];
    float s1 = a0 * wo[cA * 3 + 1] + a1 * wo[cB * 3 + 1];
    float s2 = a0 * wo[cA * 3 + 2] + a1 * wo[cB * 3 + 2];
    #pragma unroll
    for (int d = 32; d; d >>= 1) {
        s0 += __shfl_xor(s0, d);
        s1 += __shfl_xor(s1, d);
        s2 += __shfl_xor(s2, d);
    }
    if (lane < 3) {
        int v = i % V_MESH;
        float n0 = normals[(size_t)i * 3 + 0];
        float n1 = normals[(size_t)i * 3 + 1];
        float n2 = normals[(size_t)i * 3 + 2];
        float s = (lane == 0) ? s0 : (lane == 1) ? s1 : s2;
        s += n0 * wo[128 * 3 + lane] + n1 * wo[129 * 3 + lane] + n2 * wo[130 * 3 + lane];
        s += b_off[lane];
        float dd = tanhf(s);
        float lim = c_LIM[part_id[v]];
        dd = fminf(fmaxf(dd, -lim), lim);
        out_verts[(size_t)i * 3 + lane] =
            verts[(size_t)i * 3 + lane] + dd * anchor_v[(size_t)v * 3 + lane];
    }
}

extern "C" void kernel_launch(void* const* d_in, const int* in_sizes, int n_in,
                              void* d_out, int out_size, void* d_ws, size_t ws_size,
                              hipStream_t stream) {
    const float* verts    = (const float*)d_in[0];
    const float* normals  = (const float*)d_in[1];
    const float* anchor_v = (const float*)d_in[2];
    const int*   edges    = (const int*)d_in[3];
    const int*   part_id  = (const int*)d_in[4];
    const float* w0_0 = (const float*)d_in[5];
    const float* b0_0 = (const float*)d_in[6];
    const float* w1_0 = (const float*)d_in[7];
    const float* b1_0 = (const float*)d_in[8];
    const float* w0_1 = (const float*)d_in[9];
    const float* b0_1 = (const float*)d_in[10];
    const float* w1_1 = (const float*)d_in[11];
    const float* b1_1 = (const float*)d_in[12];
    const float* w0_2 = (const float*)d_in[13];
    const float* b0_2 = (const float*)d_in[14];
    const float* w1_2 = (const float*)d_in[15];
    const float* b1_2 = (const float*)d_in[16];
    const float* w_off = (const float*)d_in[17];
    const float* b_off = (const float*)d_in[18];

    float* out_verts = (float*)d_out;
    float* hout = (float*)d_out + (size_t)3 * N_TOT;   // final h (f32)

    // pair B aliases ALL of d_out (verts+h regions dead until final): [N+1][128] dwords
    unsigned* xcB = (unsigned*)d_out;

    char* p = (char*)d_ws;
    unsigned* xcA = (unsigned*)p;  p += (size_t)(N_TOT + 1) * 128 * 4;
    int*   cnt = (int*)p;          p += (size_t)N_TOT * 4;
    int*   adj = (int*)p;          p += (size_t)N_TOT * CAP * 4;
    short* Wt1 = (short*)p;        p += 256 * KP * 2;
    float* bb1 = (float*)p;        p += 256 * 4;
    short* Wt2 = (short*)p;        p += 256 * KP * 2;
    float* bb2 = (float*)p;

    hipMemsetAsync(cnt, 0, (size_t)N_TOT * 4, stream);
    hipMemsetAsync(xcA + (size_t)N_TOT * 128, 0, 512, stream);   // zero row A
    hipMemsetAsync(xcB + (size_t)N_TOT * 128, 0, 512, stream);   // zero row B
    init_adj_kernel<<<N_TOT * CAP / 1024, 256, 0, stream>>>((int4*)adj);
    fill_adj_kernel<<<(E_TOT + 255) / 256, 256, 0, stream>>>(edges, cnt, adj);
    conv_w_kernel<<<256, 256, 0, stream>>>(w0_1, b0_1, w1_1, b1_1, Wt1, bb1);
    conv_w_kernel<<<256, 256, 0, stream>>>(w0_2, b0_2, w1_2, b1_2, Wt2, bb2);

    // layer 0
    mm3_kernel<<<N_TOT / 32, 256, 0, stream>>>(normals, w0_0, b0_0, w1_0, b1_0, xcA);
    // layer 1: gather(A) -> GEMM -> B
    fused_kernel<<<N_TOT / 16, 1024, 0, stream>>>(xcA, normals, cnt, adj, Wt1, bb1, xcB);
    // layer 2: gather(B) -> GEMM -> A
    fused_kernel<<<N_TOT / 16, 1024, 0, stream>>>(xcB, normals, cnt, adj, Wt2, bb2, xcA);
    // final: gather(A) -> h + verts (writes overlay dead xcB region)
    final_fused_kernel<<<N_TOT / 4, 256, 0, stream>>>(xcA, cnt, adj, normals, verts,
                                                      anchor_v, part_id, w_off, b_off,
                                                      hout, out_verts);
}